// Round 1
// baseline (1011.939 us; speedup 1.0000x reference)
//
#include <hip/hip_runtime.h>
#include <math.h>

#define KK 4
#define BB 2
#define SS 1024
#define DD 1024
#define EPSV 1e-6f
#define BSD   (BB*SS*DD)        // 2097152
#define NBSD  (KK*BB*SS*DD)     // 8388608
#define ROWS  (KK*BB*SS)        // 8192
#define NSLOTS 64
#define NACC 24                 // 16 res + 4 pre + 4 post

// ws layout (floats):
//   [0, NSLOTS*NACC)                    slot accumulators (memset to 0 each launch)
//   [ACC_N, ACC_N+ROWS)                 inv_rms per (n,b,s) row
//   [ACC_N+ROWS, +24)                   maps: pre[4], post[4], res[16] (row-major [n][m])
#define ACC_N (NSLOTS*NACC)     // 1536

// ---------------- Kernel 1: rmsnorm stats + the 24 global dot-products ----------------
__global__ __launch_bounds__(256) void k1_reduce(const float* __restrict__ x,
                                                 const float* __restrict__ w,
                                                 const float* __restrict__ res_a,
                                                 const float* __restrict__ pre_a,
                                                 const float* __restrict__ post_a,
                                                 float* __restrict__ ws_acc,
                                                 float* __restrict__ ws_inv) {
    const int row  = blockIdx.x;        // n*B*S + b*S + s
    const int t    = threadIdx.x;       // 0..255, each handles 4 consecutive d
    const int wave = t >> 6, lane = t & 63;

    float4 xv = ((const float4*)(x + (size_t)row * DD))[t];
    float ss = xv.x*xv.x + xv.y*xv.y + xv.z*xv.z + xv.w*xv.w;
    #pragma unroll
    for (int o = 32; o > 0; o >>= 1) ss += __shfl_down(ss, o, 64);

    __shared__ float s_ss[4];
    if (lane == 0) s_ss[wave] = ss;
    __syncthreads();
    float inv = rsqrtf((s_ss[0] + s_ss[1] + s_ss[2] + s_ss[3]) * (1.0f / (float)DD) + EPSV);
    if (t == 0) ws_inv[row] = inv;

    float4 wv = ((const float4*)w)[t];
    float xn[4] = { xv.x*inv*wv.x, xv.y*inv*wv.y, xv.z*inv*wv.z, xv.w*inv*wv.w };

    float acc[NACC];
    #pragma unroll
    for (int j = 0; j < NACC; j++) acc[j] = 0.f;

    const size_t base = (size_t)row * DD + (size_t)t * 4;
    const float4* ra = (const float4*)(res_a  + base * 16);
    const float4* pa = (const float4*)(pre_a  + base * 4);
    const float4* qa = (const float4*)(post_a + base * 4);

    #pragma unroll
    for (int j = 0; j < 4; j++) {
        const float xnj = xn[j];
        #pragma unroll
        for (int q = 0; q < 4; q++) {          // res_alpha: 16 floats per d
            float4 a = ra[j*4 + q];
            acc[q*4+0] += xnj * a.x;
            acc[q*4+1] += xnj * a.y;
            acc[q*4+2] += xnj * a.z;
            acc[q*4+3] += xnj * a.w;
        }
        float4 p = pa[j];
        acc[16] += xnj * p.x; acc[17] += xnj * p.y;
        acc[18] += xnj * p.z; acc[19] += xnj * p.w;
        float4 q4 = qa[j];
        acc[20] += xnj * q4.x; acc[21] += xnj * q4.y;
        acc[22] += xnj * q4.z; acc[23] += xnj * q4.w;
    }

    // wave reduce all 24, then block reduce via LDS, then 24 atomics into a slot
    #pragma unroll
    for (int j = 0; j < NACC; j++) {
        #pragma unroll
        for (int o = 32; o > 0; o >>= 1) acc[j] += __shfl_down(acc[j], o, 64);
    }
    __shared__ float s_acc[4][NACC];
    if (lane == 0) {
        #pragma unroll
        for (int j = 0; j < NACC; j++) s_acc[wave][j] = acc[j];
    }
    __syncthreads();
    if (t < NACC) {
        float v = s_acc[0][t] + s_acc[1][t] + s_acc[2][t] + s_acc[3][t];
        atomicAdd(&ws_acc[(blockIdx.x & (NSLOTS-1)) * NACC + t], v);
    }
}

// ---------------- Kernel 2: fold slots, sigmoids, 4x4 log-Sinkhorn ----------------
__global__ void k2_maps(const float* __restrict__ ws_acc,
                        const float* __restrict__ res_beta,
                        const float* __restrict__ pre_beta,
                        const float* __restrict__ post_beta,
                        float* __restrict__ maps) {
    if (threadIdx.x != 0 || blockIdx.x != 0) return;
    float h[NACC];
    for (int j = 0; j < NACC; j++) {
        float s = 0.f;
        for (int sl = 0; sl < NSLOTS; sl++) s += ws_acc[sl*NACC + j];
        h[j] = s;
    }
    for (int i = 0; i < 4; i++) {
        float hp = 1e-4f * h[16+i] + pre_beta[i];
        maps[i]     = 1.f / (1.f + expf(-hp));          // pre_mapping (scale 1.0)
        float hq = 1e-4f * h[20+i] + post_beta[i];
        maps[4+i]   = 2.f / (1.f + expf(-hq));          // post_mapping (scale 2.0)
    }
    // Sinkhorn on Z = (1e-4*h_res + res_beta[col]) / 0.05
    float Z[4][4];
    for (int i = 0; i < 4; i++)
        for (int j = 0; j < 4; j++)
            Z[i][j] = (1e-4f * h[i*4 + j] + res_beta[j]) * (1.0f / 0.05f);
    float u[4] = {0,0,0,0}, v[4] = {0,0,0,0};
    for (int it = 0; it < 20; it++) {
        for (int i = 0; i < 4; i++) {
            float m = Z[i][0]+v[0];
            for (int j = 1; j < 4; j++) { float tt = Z[i][j]+v[j]; m = tt > m ? tt : m; }
            float s = 0.f;
            for (int j = 0; j < 4; j++) s += expf(Z[i][j]+v[j]-m);
            u[i] = -(m + logf(s));
        }
        for (int j = 0; j < 4; j++) {
            float m = Z[0][j]+u[0];
            for (int i = 1; i < 4; i++) { float tt = Z[i][j]+u[i]; m = tt > m ? tt : m; }
            float s = 0.f;
            for (int i = 0; i < 4; i++) s += expf(Z[i][j]+u[i]-m);
            v[j] = -(m + logf(s));
        }
    }
    for (int i = 0; i < 4; i++)
        for (int j = 0; j < 4; j++)
            maps[8 + i*4 + j] = expf(Z[i][j] + u[i] + v[j]);   // res_map[n][m]
}

// ---------------- Kernel 3: outputs ----------------
__global__ __launch_bounds__(256) void k3_out(const float* __restrict__ x,
                                              const float* __restrict__ w,
                                              const float* __restrict__ ws_inv,
                                              const float* __restrict__ maps,
                                              float* __restrict__ out) {
    const int tid = blockIdx.x * 256 + threadIdx.x;   // one float4 of (b,s,d)
    const size_t e = (size_t)tid * 4;
    const int bs = (int)(e >> 10);                    // e / D

    float pre_m[4], post_m[4], rm[16];
    #pragma unroll
    for (int i = 0; i < 4; i++)  { pre_m[i] = maps[i]; post_m[i] = maps[4+i]; }
    #pragma unroll
    for (int i = 0; i < 16; i++) rm[i] = maps[8+i];

    float4 wv = *(const float4*)(w + (e & (DD-1)));

    float li_x = 0.f, li_y = 0.f, li_z = 0.f, li_w = 0.f;
    float4 res[4];
    #pragma unroll
    for (int m = 0; m < 4; m++) res[m] = make_float4(0.f, 0.f, 0.f, 0.f);

    #pragma unroll
    for (int n = 0; n < 4; n++) {
        const float iv = ws_inv[n * (BB*SS) + bs];
        float4 xv = *(const float4*)(x + (size_t)n * BSD + e);
        float xnx = xv.x * iv * wv.x;
        float xny = xv.y * iv * wv.y;
        float xnz = xv.z * iv * wv.z;
        float xnw = xv.w * iv * wv.w;
        const float pm = pre_m[n];
        li_x += xnx * pm; li_y += xny * pm; li_z += xnz * pm; li_w += xnw * pm;
        #pragma unroll
        for (int m = 0; m < 4; m++) {
            const float r = rm[n*4 + m];
            res[m].x += xnx * r; res[m].y += xny * r;
            res[m].z += xnz * r; res[m].w += xnw * r;
        }
    }
    // res_out first: out[m*BSD + e]
    #pragma unroll
    for (int m = 0; m < 4; m++)
        *(float4*)(out + (size_t)m * BSD + e) = res[m];
    // then post_out: out[NBSD + n*BSD + e]
    #pragma unroll
    for (int n = 0; n < 4; n++) {
        const float pm = post_m[n];
        *(float4*)(out + (size_t)NBSD + (size_t)n * BSD + e) =
            make_float4(li_x * pm, li_y * pm, li_z * pm, li_w * pm);
    }
}

extern "C" void kernel_launch(void* const* d_in, const int* in_sizes, int n_in,
                              void* d_out, int out_size, void* d_ws, size_t ws_size,
                              hipStream_t stream) {
    const float* x      = (const float*)d_in[0];
    const float* w      = (const float*)d_in[1];
    const float* res_a  = (const float*)d_in[2];
    const float* pre_a  = (const float*)d_in[3];
    const float* post_a = (const float*)d_in[4];
    const float* res_b  = (const float*)d_in[5];
    const float* pre_b  = (const float*)d_in[6];
    const float* post_b = (const float*)d_in[7];

    float* ws      = (float*)d_ws;
    float* ws_acc  = ws;                      // NSLOTS*NACC floats
    float* ws_inv  = ws + ACC_N;              // ROWS floats
    float* ws_maps = ws + ACC_N + ROWS;       // 24 floats

    hipMemsetAsync(ws_acc, 0, NSLOTS * NACC * sizeof(float), stream);

    k1_reduce<<<ROWS, 256, 0, stream>>>(x, w, res_a, pre_a, post_a, ws_acc, ws_inv);
    k2_maps<<<1, 64, 0, stream>>>(ws_acc, res_b, pre_b, post_b, ws_maps);
    k3_out<<<BSD/1024, 256, 0, stream>>>(x, w, ws_inv, ws_maps, (float*)d_out);
}

// Round 2
// 930.168 us; speedup vs baseline: 1.0879x; 1.0879x over previous
//
#include <hip/hip_runtime.h>
#include <math.h>

#define KK 4
#define BB 2
#define SS 1024
#define DD 1024
#define EPSV 1e-6f
#define BSD   (BB*SS*DD)        // 2097152
#define NBSD  (KK*BB*SS*DD)     // 8388608
#define ROWS  (KK*BB*SS)        // 8192
#define NSLOTS 64
#define NACC 24                 // 16 res + 4 pre + 4 post
#define ACC_N (NSLOTS*NACC)     // 1536

// ---------------- Kernel 1: rmsnorm stats + the 24 global dot-products ----------------
// Coalesced version: xn row staged in LDS; alpha rows swept with wave-contiguous
// float4 loads (64 lanes x 16B = 1KB/instruction, 16 lines vs 64 for the old
// 256B-strided pattern).
__global__ __launch_bounds__(256) void k1_reduce(const float* __restrict__ x,
                                                 const float* __restrict__ w,
                                                 const float* __restrict__ res_a,
                                                 const float* __restrict__ pre_a,
                                                 const float* __restrict__ post_a,
                                                 float* __restrict__ ws_acc,
                                                 float* __restrict__ ws_inv) {
    const int row  = blockIdx.x;        // n*B*S + b*S + s
    const int t    = threadIdx.x;       // 0..255
    const int wave = t >> 6, lane = t & 63;

    __shared__ float s_xn[DD];          // 4 KB normalized row
    __shared__ float s_ss[4];

    float4 xv = ((const float4*)(x + (size_t)row * DD))[t];
    float ss = xv.x*xv.x + xv.y*xv.y + xv.z*xv.z + xv.w*xv.w;
    #pragma unroll
    for (int o = 32; o > 0; o >>= 1) ss += __shfl_down(ss, o, 64);
    if (lane == 0) s_ss[wave] = ss;
    __syncthreads();
    float inv = rsqrtf((s_ss[0] + s_ss[1] + s_ss[2] + s_ss[3]) * (1.0f / (float)DD) + EPSV);
    if (t == 0) ws_inv[row] = inv;

    float4 wv = ((const float4*)w)[t];
    ((float4*)s_xn)[t] = make_float4(xv.x*inv*wv.x, xv.y*inv*wv.y,
                                     xv.z*inv*wv.z, xv.w*inv*wv.w);
    __syncthreads();

    // --- res_alpha: 16384 floats/row = 4096 float4. float4 g covers d=g>>2,
    // m16 = 4*(g&3)+{0..3}. Thread t's class (t&3) is fixed -> 4 accumulators.
    float ar[4] = {0.f, 0.f, 0.f, 0.f};
    const float4* ra = (const float4*)(res_a + (size_t)row * DD * 16);
    #pragma unroll
    for (int c = 0; c < 16; c++) {
        float4 a = ra[c * 256 + t];
        float xs = s_xn[c * 64 + (t >> 2)];
        ar[0] += xs * a.x; ar[1] += xs * a.y;
        ar[2] += xs * a.z; ar[3] += xs * a.w;
    }

    // --- pre/post: 4096 floats/row = 1024 float4; float4 g covers d=g, m=0..3.
    float ap[4] = {0.f,0.f,0.f,0.f}, aq[4] = {0.f,0.f,0.f,0.f};
    const float4* pa = (const float4*)(pre_a  + (size_t)row * DD * 4);
    const float4* qa = (const float4*)(post_a + (size_t)row * DD * 4);
    #pragma unroll
    for (int c = 0; c < 4; c++) {
        float xs = s_xn[c * 256 + t];
        float4 p = pa[c * 256 + t];
        ap[0] += xs * p.x; ap[1] += xs * p.y;
        ap[2] += xs * p.z; ap[3] += xs * p.w;
        float4 q = qa[c * 256 + t];
        aq[0] += xs * q.x; aq[1] += xs * q.y;
        aq[2] += xs * q.z; aq[3] += xs * q.w;
    }

    // --- reduce: res over residue-4 lane classes; pre/post over full wave.
    #pragma unroll
    for (int j = 0; j < 4; j++) {
        #pragma unroll
        for (int o = 32; o >= 4; o >>= 1) ar[j] += __shfl_down(ar[j], o, 64);
        #pragma unroll
        for (int o = 32; o >= 1; o >>= 1) {
            ap[j] += __shfl_down(ap[j], o, 64);
            aq[j] += __shfl_down(aq[j], o, 64);
        }
    }
    __shared__ float s_red[4][NACC];
    if (lane < 4) {             // lane i holds res m16 = 4*i + {0..3}
        #pragma unroll
        for (int j = 0; j < 4; j++) s_red[wave][lane*4 + j] = ar[j];
    }
    if (lane == 0) {
        #pragma unroll
        for (int j = 0; j < 4; j++) { s_red[wave][16 + j] = ap[j]; s_red[wave][20 + j] = aq[j]; }
    }
    __syncthreads();
    if (t < NACC) {
        float v = s_red[0][t] + s_red[1][t] + s_red[2][t] + s_red[3][t];
        atomicAdd(&ws_acc[(row & (NSLOTS-1)) * NACC + t], v);
    }
}

// ---------------- Kernel 2: fold slots, sigmoids, 4x4 log-Sinkhorn ----------------
__global__ void k2_maps(const float* __restrict__ ws_acc,
                        const float* __restrict__ res_beta,
                        const float* __restrict__ pre_beta,
                        const float* __restrict__ post_beta,
                        float* __restrict__ maps) {
    if (threadIdx.x != 0 || blockIdx.x != 0) return;
    float h[NACC];
    for (int j = 0; j < NACC; j++) {
        float s = 0.f;
        for (int sl = 0; sl < NSLOTS; sl++) s += ws_acc[sl*NACC + j];
        h[j] = s;
    }
    for (int i = 0; i < 4; i++) {
        float hp = 1e-4f * h[16+i] + pre_beta[i];
        maps[i]     = 1.f / (1.f + expf(-hp));          // pre_mapping (scale 1.0)
        float hq = 1e-4f * h[20+i] + post_beta[i];
        maps[4+i]   = 2.f / (1.f + expf(-hq));          // post_mapping (scale 2.0)
    }
    float Z[4][4];
    for (int i = 0; i < 4; i++)
        for (int j = 0; j < 4; j++)
            Z[i][j] = (1e-4f * h[i*4 + j] + res_beta[j]) * (1.0f / 0.05f);
    float u[4] = {0,0,0,0}, v[4] = {0,0,0,0};
    for (int it = 0; it < 20; it++) {
        for (int i = 0; i < 4; i++) {
            float m = Z[i][0]+v[0];
            for (int j = 1; j < 4; j++) { float tt = Z[i][j]+v[j]; m = tt > m ? tt : m; }
            float s = 0.f;
            for (int j = 0; j < 4; j++) s += expf(Z[i][j]+v[j]-m);
            u[i] = -(m + logf(s));
        }
        for (int j = 0; j < 4; j++) {
            float m = Z[0][j]+u[0];
            for (int i = 1; i < 4; i++) { float tt = Z[i][j]+u[i]; m = tt > m ? tt : m; }
            float s = 0.f;
            for (int i = 0; i < 4; i++) s += expf(Z[i][j]+u[i]-m);
            v[j] = -(m + logf(s));
        }
    }
    for (int i = 0; i < 4; i++)
        for (int j = 0; j < 4; j++)
            maps[8 + i*4 + j] = expf(Z[i][j] + u[i] + v[j]);   // res_map[n][m]
}

// ---------------- Kernel 3: outputs ----------------
__global__ __launch_bounds__(256) void k3_out(const float* __restrict__ x,
                                              const float* __restrict__ w,
                                              const float* __restrict__ ws_inv,
                                              const float* __restrict__ maps,
                                              float* __restrict__ out) {
    const int tid = blockIdx.x * 256 + threadIdx.x;   // one float4 of (b,s,d)
    const size_t e = (size_t)tid * 4;
    const int bs = (int)(e >> 10);                    // e / D

    float pre_m[4], post_m[4], rm[16];
    #pragma unroll
    for (int i = 0; i < 4; i++)  { pre_m[i] = maps[i]; post_m[i] = maps[4+i]; }
    #pragma unroll
    for (int i = 0; i < 16; i++) rm[i] = maps[8+i];

    float4 wv = *(const float4*)(w + (e & (DD-1)));

    float li_x = 0.f, li_y = 0.f, li_z = 0.f, li_w = 0.f;
    float4 res[4];
    #pragma unroll
    for (int m = 0; m < 4; m++) res[m] = make_float4(0.f, 0.f, 0.f, 0.f);

    #pragma unroll
    for (int n = 0; n < 4; n++) {
        const float iv = ws_inv[n * (BB*SS) + bs];
        float4 xv = *(const float4*)(x + (size_t)n * BSD + e);
        float xnx = xv.x * iv * wv.x;
        float xny = xv.y * iv * wv.y;
        float xnz = xv.z * iv * wv.z;
        float xnw = xv.w * iv * wv.w;
        const float pm = pre_m[n];
        li_x += xnx * pm; li_y += xny * pm; li_z += xnz * pm; li_w += xnw * pm;
        #pragma unroll
        for (int m = 0; m < 4; m++) {
            const float r = rm[n*4 + m];
            res[m].x += xnx * r; res[m].y += xny * r;
            res[m].z += xnz * r; res[m].w += xnw * r;
        }
    }
    #pragma unroll
    for (int m = 0; m < 4; m++)
        *(float4*)(out + (size_t)m * BSD + e) = res[m];
    #pragma unroll
    for (int n = 0; n < 4; n++) {
        const float pm = post_m[n];
        *(float4*)(out + (size_t)NBSD + (size_t)n * BSD + e) =
            make_float4(li_x * pm, li_y * pm, li_z * pm, li_w * pm);
    }
}

extern "C" void kernel_launch(void* const* d_in, const int* in_sizes, int n_in,
                              void* d_out, int out_size, void* d_ws, size_t ws_size,
                              hipStream_t stream) {
    const float* x      = (const float*)d_in[0];
    const float* w      = (const float*)d_in[1];
    const float* res_a  = (const float*)d_in[2];
    const float* pre_a  = (const float*)d_in[3];
    const float* post_a = (const float*)d_in[4];
    const float* res_b  = (const float*)d_in[5];
    const float* pre_b  = (const float*)d_in[6];
    const float* post_b = (const float*)d_in[7];

    float* ws      = (float*)d_ws;
    float* ws_acc  = ws;                      // NSLOTS*NACC floats
    float* ws_inv  = ws + ACC_N;              // ROWS floats
    float* ws_maps = ws + ACC_N + ROWS;       // 24 floats

    hipMemsetAsync(ws_acc, 0, NSLOTS * NACC * sizeof(float), stream);

    k1_reduce<<<ROWS, 256, 0, stream>>>(x, w, res_a, pre_a, post_a, ws_acc, ws_inv);
    k2_maps<<<1, 64, 0, stream>>>(ws_acc, res_b, pre_b, post_b, ws_maps);
    k3_out<<<BSD/1024, 256, 0, stream>>>(x, w, ws_inv, ws_maps, (float*)d_out);
}